// Round 3
// baseline (682.055 us; speedup 1.0000x reference)
//
#include <hip/hip_runtime.h>
#include <math.h>
#include <limits.h>

#define NCHUNK 16
#define LDS_CAP 8000        // chunk floats; V=128000 / 16 = 8000
#define PLACEHOLDER (-1)

typedef float f32x4 __attribute__((ext_vector_type(4)));

// Combine (max, sum-of-exp-relative-to-max). Guard for -inf partials.
__device__ __forceinline__ void comb_ms(float& m, float& s, float m2, float s2) {
  if (m2 > m) {
    s = s * expf(m - m2) + s2;
    m = m2;
  } else if (m2 != -INFINITY) {
    s += s2 * expf(m2 - m);
  }
}

// (max, index) with first-occurrence tie-break (lower index wins).
__device__ __forceinline__ void comb_mx(float& m, int& i, float m2, int i2) {
  if (m2 > m || (m2 == m && i2 < i)) { m = m2; i = i2; }
}

__global__ __launch_bounds__(256, 4) void k_fused(
    const float* __restrict__ logits, const float* __restrict__ draft,
    const int* __restrict__ dids, const int* __restrict__ bonus,
    const int* __restrict__ topk, const float* __restrict__ uniform,
    const float* __restrict__ invq,
    float* __restrict__ pm, float* __restrict__ ps, int* __restrict__ pidx,
    float* __restrict__ psm, int* __restrict__ psi,
    int* __restrict__ rowAcc, int* __restrict__ cnt, int* __restrict__ done,
    int B, int S, int V, int chunk_elems, int nitems,
    int* __restrict__ out) {
  __shared__ float lds_l[LDS_CAP];
  __shared__ float shf[4];
  __shared__ float shs[4];
  __shared__ int   shi[4];
  __shared__ float sM, sInvZ;
  __shared__ int   doFin;
  __shared__ int   rec[4], tam[4];

  const int tid = threadIdx.x;
  const int lane = tid & 63;
  const int wv = tid >> 6;
  const int doneTarget = NCHUNK * S;

  for (int item = blockIdx.x; item < nitems; item += gridDim.x) {
    const int row = item / NCHUNK;
    const int chunk = item & (NCHUNK - 1);
    const int b = row / S;
    const bool greedy = (topk[b] == 1);
    const int begin = chunk * chunk_elems;
    const int c4 = chunk_elems >> 2;
    const f32x4* l4 = (const f32x4*)(logits + (size_t)row * V) + (begin >> 2);

    if (greedy) {
      // ---- greedy row: argmax of logits only; no softmax, no phase B ----
      float m = -INFINITY; int mi = INT_MAX;
      for (int i = tid; i < c4; i += 256) {
        f32x4 v = __builtin_nontemporal_load(l4 + i);
        const int gi = begin + (i << 2);
#pragma unroll
        for (int k = 0; k < 4; ++k)
          if (v[k] > m) { m = v[k]; mi = gi + k; }   // strict >: first idx kept
      }
      for (int off = 32; off; off >>= 1) {
        float m2 = __shfl_xor(m, off);
        int   i2 = __shfl_xor(mi, off);
        comb_mx(m, mi, m2, i2);
      }
      if (lane == 0) { shf[wv] = m; shi[wv] = mi; }
      __syncthreads();
      if (tid == 0) {
#pragma unroll
        for (int w = 1; w < 4; ++w) comb_mx(m, mi, shf[w], shi[w]);
        pm[item] = m; pidx[item] = mi;
        __threadfence();
        int old = __hip_atomic_fetch_add(&done[b], 1, __ATOMIC_ACQ_REL,
                                         __HIP_MEMORY_SCOPE_AGENT);
        doFin = (old == doneTarget - 1);
      }
      __syncthreads();
    } else {
      // ---- random row, phase A: stage logits chunk to LDS + online {M,Z} ----
      float m = -INFINITY, ssum = 0.f;
      for (int i = tid; i < c4; i += 256) {
        f32x4 v = __builtin_nontemporal_load(l4 + i);
        *(f32x4*)&lds_l[i << 2] = v;
#pragma unroll
        for (int k = 0; k < 4; ++k) {
          float x = v[k];
          if (x > m) { ssum = ssum * expf(m - x) + 1.f; m = x; }
          else       { ssum += expf(x - m); }
        }
      }
      for (int off = 32; off; off >>= 1) {
        float m2 = __shfl_xor(m, off);
        float s2 = __shfl_xor(ssum, off);
        comb_ms(m, ssum, m2, s2);
      }
      if (lane == 0) { shf[wv] = m; shs[wv] = ssum; }
      __syncthreads();
      if (tid == 0) {
#pragma unroll
        for (int w = 1; w < 4; ++w) comb_ms(m, ssum, shf[w], shs[w]);
        pm[item] = m; ps[item] = ssum;
        __threadfence();
        __hip_atomic_fetch_add(&cnt[row], 1, __ATOMIC_RELEASE,
                               __HIP_MEMORY_SCOPE_AGENT);
        // spin for the row's 16 chunk partials (peers are consecutive
        // block ids at the same item index -> co-resident -> no deadlock)
        while (__hip_atomic_load(&cnt[row], __ATOMIC_ACQUIRE,
                                 __HIP_MEMORY_SCOPE_AGENT) < NCHUNK)
          __builtin_amdgcn_s_sleep(2);
        // linear combine, identical order in all 16 blocks -> identical M,Z
        float M = -INFINITY, Z = 0.f;
        for (int c = 0; c < NCHUNK; ++c) {
          float mm = __hip_atomic_load(&pm[row * NCHUNK + c], __ATOMIC_RELAXED,
                                       __HIP_MEMORY_SCOPE_AGENT);
          float ss = __hip_atomic_load(&ps[row * NCHUNK + c], __ATOMIC_RELAXED,
                                       __HIP_MEMORY_SCOPE_AGENT);
          comb_ms(M, Z, mm, ss);
        }
        sM = M; sInvZ = 1.0f / Z;
      }
      __syncthreads();
      const float M = sM, invZ = sInvZ;

      // accept decision by the chunk that owns the draft token (from LDS)
      const int tok = dids[row];
      if (tid == 0 && tok >= begin && tok < begin + chunk_elems) {
        float t_at = expf(lds_l[tok - begin] - M) * invZ;
        float d_at = draft[(size_t)row * V + tok];
        float u = uniform[row];
        rowAcc[row] = (d_at > 0.f && (t_at / d_at) >= u) ? 1 : 0;
      }

      // ---- phase B: score argmax from LDS logits + streamed draft/invq ----
      const f32x4* d4 = (const f32x4*)(draft + (size_t)row * V) + (begin >> 2);
      const f32x4* q4 = (const f32x4*)(invq + (size_t)b * V) + (begin >> 2);
      float smx = -INFINITY; int si = INT_MAX;
      for (int i = tid; i < c4; i += 256) {
        f32x4 lv = *(const f32x4*)&lds_l[i << 2];
        f32x4 dv = __builtin_nontemporal_load(d4 + i);
        f32x4 qv = q4[i];
        const int gi = begin + (i << 2);
#pragma unroll
        for (int k = 0; k < 4; ++k) {
          float p = expf(lv[k] - M) * invZ;
          float sc = fmaxf(p - dv[k], 0.f) * qv[k];
          if (sc > smx) { smx = sc; si = gi + k; }
        }
      }
      for (int off = 32; off; off >>= 1) {
        float m2 = __shfl_xor(smx, off);
        int   i2 = __shfl_xor(si, off);
        comb_mx(smx, si, m2, i2);
      }
      if (lane == 0) { shf[wv] = smx; shi[wv] = si; }
      __syncthreads();
      if (tid == 0) {
#pragma unroll
        for (int w = 1; w < 4; ++w) comb_mx(smx, si, shf[w], shi[w]);
        psm[item] = smx; psi[item] = si;
        __threadfence();
        int old = __hip_atomic_fetch_add(&done[b], 1, __ATOMIC_ACQ_REL,
                                         __HIP_MEMORY_SCOPE_AGENT);
        doFin = (old == doneTarget - 1);
      }
      __syncthreads();
    }

    // ---- finalize batch row b (last arriver only) ----
    if (doFin) {
      if (tid < 64) {
        const int s = tid >> 4;
        const int c = tid & 15;
        float mv = -INFINITY; int iv = INT_MAX;
        if (s < S) {
          const int oo = (b * S + s) * NCHUNK + c;
          if (greedy) {
            mv = __hip_atomic_load(&pm[oo], __ATOMIC_RELAXED, __HIP_MEMORY_SCOPE_AGENT);
            iv = __hip_atomic_load(&pidx[oo], __ATOMIC_RELAXED, __HIP_MEMORY_SCOPE_AGENT);
          } else {
            mv = __hip_atomic_load(&psm[oo], __ATOMIC_RELAXED, __HIP_MEMORY_SCOPE_AGENT);
            iv = __hip_atomic_load(&psi[oo], __ATOMIC_RELAXED, __HIP_MEMORY_SCOPE_AGENT);
          }
        }
        for (int off = 8; off; off >>= 1) {
          float m2 = __shfl_xor(mv, off);
          int   i2 = __shfl_xor(iv, off);
          comb_mx(mv, iv, m2, i2);
        }
        if (c == 0 && s < S) { if (greedy) tam[s] = iv; else rec[s] = iv; }
      }
      __syncthreads();
      if (tid == 0) {
        int tokv[9];
        bool rejected_before = false, any_rej = false;
        for (int ss = 0; ss < S; ++ss) {
          const int r = b * S + ss;
          const int dtok = dids[r];
          int t; bool rej;
          if (greedy) {
            const int ta = tam[ss];
            rej = (dtok != ta);
            t = ta;
          } else {
            const int a = __hip_atomic_load(&rowAcc[r], __ATOMIC_RELAXED,
                                            __HIP_MEMORY_SCOPE_AGENT);
            rej = !a;
            t = a ? dtok : rec[ss];
          }
          tokv[ss] = rejected_before ? PLACEHOLDER : t;
          any_rej = any_rej || rej;
          rejected_before = rejected_before || rej;
        }
        tokv[S] = any_rej ? PLACEHOLDER : bonus[b];
        int na = 0;
        const int Sp1 = S + 1;
        for (int j = 0; j < Sp1; ++j) na += (tokv[j] != PLACEHOLDER);
        for (int j = 0; j < Sp1; ++j) out[b * Sp1 + j] = tokv[j];
        out[B * Sp1 + b] = Sp1 - na;            // num_rejected_tokens
        out[B * Sp1 + B + b] = tokv[na - 1];    // last_token_ids
      }
    }
    __syncthreads();  // protect shared reuse across items
  }
}

extern "C" void kernel_launch(void* const* d_in, const int* in_sizes, int n_in,
                              void* d_out, int out_size, void* d_ws, size_t ws_size,
                              hipStream_t stream) {
  const float* logits = (const float*)d_in[0];
  const float* draft  = (const float*)d_in[1];
  const int*   dids   = (const int*)d_in[2];
  const int*   bonus  = (const int*)d_in[3];
  const int*   topk   = (const int*)d_in[4];
  const float* unif   = (const float*)d_in[5];
  const float* invq   = (const float*)d_in[6];
  int* out = (int*)d_out;

  const int B = in_sizes[3];
  const int S = in_sizes[2] / B;
  const int V = in_sizes[0] / in_sizes[2];
  const int nrows = B * S;
  const int nitems = nrows * NCHUNK;
  const int chunk_elems = V / NCHUNK;   // 8000 for V=128000 (== LDS_CAP)

  char* w = (char*)d_ws;
  float* pm   = (float*)w; w += (size_t)nitems * sizeof(float);
  float* ps   = (float*)w; w += (size_t)nitems * sizeof(float);
  int*   pidx = (int*)w;   w += (size_t)nitems * sizeof(int);
  float* psm  = (float*)w; w += (size_t)nitems * sizeof(float);
  int*   psi  = (int*)w;   w += (size_t)nitems * sizeof(int);
  int* rowAcc = (int*)w;   w += (size_t)nrows * sizeof(int);
  int* cnt    = (int*)w;   w += (size_t)nrows * sizeof(int);
  int* done   = (int*)w;   w += (size_t)B * sizeof(int);

  // reset sync counters every call (graph-replay determinism); cnt+done contiguous
  hipMemsetAsync(cnt, 0, (size_t)(nrows + B) * sizeof(int), stream);

  const int grid = nitems < 1024 ? nitems : 1024;
  k_fused<<<dim3(grid), dim3(256), 0, stream>>>(
      logits, draft, dids, bonus, topk, unif, invq,
      pm, ps, pidx, psm, psi, rowAcc, cnt, done,
      B, S, V, chunk_elems, nitems, out);
}

// Round 4
// 531.739 us; speedup vs baseline: 1.2827x; 1.2827x over previous
//
#include <hip/hip_runtime.h>
#include <math.h>
#include <limits.h>

#define NCHUNK 32
#define LDS_CAP 4096        // floats; chunk_elems = V/NCHUNK = 4000 for V=128000
#define PLACEHOLDER (-1)

typedef float f32x4 __attribute__((ext_vector_type(4)));

// Combine (max, sum-of-exp-relative-to-max). Guards for -inf partials.
__device__ __forceinline__ void comb_ms(float& m, float& s, float m2, float s2) {
  if (m2 > m) {
    s = s * expf(m - m2) + s2;
    m = m2;
  } else if (m2 != -INFINITY) {
    s += s2 * expf(m2 - m);
  }
}

// (max, index) with first-occurrence tie-break (lower index wins).
__device__ __forceinline__ void comb_mx(float& m, int& i, float m2, int i2) {
  if (m2 > m || (m2 == m && i2 < i)) { m = m2; i = i2; }
}

// One pass over logits. Each block handles one (row, chunk) item per
// grid-stride iteration: stages its 16 KB logits chunk to LDS while computing
// online {max, sumexp}; publishes the partial (release); relaxed-spins for the
// row's 32 peers; then computes the score argmax reading logits from LDS.
// Deadlock-free: a block always publishes BEFORE spinning and cnt is
// monotone, so the wait graph has no cycle; gridDim % NCHUNK == 0 keeps all
// 32 peers of a row in the same grid-stride iteration.
__global__ __launch_bounds__(256, 8) void k_fused(
    const float* __restrict__ logits, const float* __restrict__ draft,
    const int* __restrict__ topk, const float* __restrict__ invq,
    float* __restrict__ pm, float* __restrict__ ps, int* __restrict__ pidx,
    float* __restrict__ psm, int* __restrict__ psi,
    int* __restrict__ cnt,
    int S, int V, int chunk_elems, int nitems) {
  __shared__ float lds_l[LDS_CAP];
  __shared__ float shf[4];
  __shared__ float shs[4];
  __shared__ int   shi[4];
  __shared__ float sM, sInvZ;

  const int tid = threadIdx.x;
  const int lane = tid & 63;
  const int wv = tid >> 6;

  for (int item = blockIdx.x; item < nitems; item += gridDim.x) {
    const int row = item / NCHUNK;
    const int chunk = item & (NCHUNK - 1);
    const int b = row / S;
    const bool greedy = (topk[b] == 1);
    const int begin = chunk * chunk_elems;
    const int end = min(begin + chunk_elems, V);
    const int n = max(end - begin, 0);
    const int c4 = n >> 2;
    const float* lrow = logits + (size_t)row * V;
    const f32x4* l4 = (const f32x4*)(lrow + begin);

    if (greedy) {
      // ---- greedy row: argmax of logits only ----
      float m = -INFINITY; int mi = INT_MAX;
      for (int i = tid; i < c4; i += 256) {
        f32x4 v = l4[i];
        const int gi = begin + (i << 2);
#pragma unroll
        for (int k = 0; k < 4; ++k)
          if (v[k] > m) { m = v[k]; mi = gi + k; }   // strict >: first idx kept
      }
      for (int j = begin + (c4 << 2) + tid; j < end; j += 256) {
        float x = lrow[j];
        if (x > m) { m = x; mi = j; }
      }
      for (int off = 32; off; off >>= 1) {
        float m2 = __shfl_xor(m, off);
        int   i2 = __shfl_xor(mi, off);
        comb_mx(m, mi, m2, i2);
      }
      if (lane == 0) { shf[wv] = m; shi[wv] = mi; }
      __syncthreads();
      if (tid == 0) {
#pragma unroll
        for (int w = 1; w < 4; ++w) comb_mx(m, mi, shf[w], shi[w]);
        pm[item] = m; pidx[item] = mi;
      }
      __syncthreads();   // shf/shi reuse safety before next item
      continue;
    }

    // ---- phase A: stage logits chunk to LDS + online {M,Z} ----
    float m = -INFINITY, ssum = 0.f;
    for (int i = tid; i < c4; i += 256) {
      f32x4 v = l4[i];
      *(f32x4*)&lds_l[i << 2] = v;
#pragma unroll
      for (int k = 0; k < 4; ++k) {
        float x = v[k];
        if (x > m) { ssum = ssum * expf(m - x) + 1.f; m = x; }
        else       { ssum += expf(x - m); }
      }
    }
    for (int j = begin + (c4 << 2) + tid; j < end; j += 256) {
      float x = lrow[j];
      lds_l[j - begin] = x;
      if (x > m) { ssum = ssum * expf(m - x) + 1.f; m = x; }
      else       { ssum += expf(x - m); }
    }
    for (int off = 32; off; off >>= 1) {
      float m2 = __shfl_xor(m, off);
      float s2 = __shfl_xor(ssum, off);
      comb_ms(m, ssum, m2, s2);
    }
    if (lane == 0) { shf[wv] = m; shs[wv] = ssum; }
    __syncthreads();
    if (tid == 0) {
#pragma unroll
      for (int w = 1; w < 4; ++w) comb_ms(m, ssum, shf[w], shs[w]);
      __hip_atomic_store(&pm[item], m, __ATOMIC_RELAXED, __HIP_MEMORY_SCOPE_AGENT);
      __hip_atomic_store(&ps[item], ssum, __ATOMIC_RELAXED, __HIP_MEMORY_SCOPE_AGENT);
      // publish (release), THEN spin with relaxed loads (no per-poll
      // cache invalidates), then one acquire fence.
      __hip_atomic_fetch_add(&cnt[row], 1, __ATOMIC_RELEASE,
                             __HIP_MEMORY_SCOPE_AGENT);
      while (__hip_atomic_load(&cnt[row], __ATOMIC_RELAXED,
                               __HIP_MEMORY_SCOPE_AGENT) < NCHUNK)
        __builtin_amdgcn_s_sleep(8);
      __threadfence();
      // linear combine, identical order in all 32 blocks -> identical M,Z
      float M = -INFINITY, Z = 0.f;
      for (int c = 0; c < NCHUNK; ++c) {
        float mm = __hip_atomic_load(&pm[row * NCHUNK + c], __ATOMIC_RELAXED,
                                     __HIP_MEMORY_SCOPE_AGENT);
        float ss = __hip_atomic_load(&ps[row * NCHUNK + c], __ATOMIC_RELAXED,
                                     __HIP_MEMORY_SCOPE_AGENT);
        comb_ms(M, Z, mm, ss);
      }
      sM = M; sInvZ = 1.0f / Z;
    }
    __syncthreads();
    const float M = sM, invZ = sInvZ;

    // ---- phase B: score argmax from LDS logits + streamed draft/invq ----
    const f32x4* d4 = (const f32x4*)(draft + (size_t)row * V + begin);
    const f32x4* q4 = (const f32x4*)(invq + (size_t)b * V + begin);
    float smx = -INFINITY; int si = INT_MAX;
    for (int i = tid; i < c4; i += 256) {
      f32x4 lv = *(const f32x4*)&lds_l[i << 2];
      f32x4 dv = __builtin_nontemporal_load(d4 + i);  // stream, don't pollute
      f32x4 qv = q4[i];                                // reused across S rows
      const int gi = begin + (i << 2);
#pragma unroll
      for (int k = 0; k < 4; ++k) {
        float p = expf(lv[k] - M) * invZ;
        float sc = fmaxf(p - dv[k], 0.f) * qv[k];
        if (sc > smx) { smx = sc; si = gi + k; }
      }
    }
    for (int j = begin + (c4 << 2) + tid; j < end; j += 256) {
      float p = expf(lds_l[j - begin] - M) * invZ;
      float sc = fmaxf(p - draft[(size_t)row * V + j], 0.f)
               * invq[(size_t)b * V + j];
      if (sc > smx) { smx = sc; si = j; }
    }
    for (int off = 32; off; off >>= 1) {
      float m2 = __shfl_xor(smx, off);
      int   i2 = __shfl_xor(si, off);
      comb_mx(smx, si, m2, i2);
    }
    if (lane == 0) { shf[wv] = smx; shi[wv] = si; }
    __syncthreads();
    if (tid == 0) {
#pragma unroll
      for (int w = 1; w < 4; ++w) comb_mx(smx, si, shf[w], shi[w]);
      psm[item] = smx; psi[item] = si;
    }
    __syncthreads();   // shared reuse safety before next item
  }
}

// Finalize: one block (64 threads) per batch element b.
__global__ __launch_bounds__(64) void k_finalize(
    const float* __restrict__ logits, const float* __restrict__ draft,
    const int* __restrict__ dids, const int* __restrict__ bonus,
    const int* __restrict__ topk, const float* __restrict__ uniform,
    const float* __restrict__ pm, const float* __restrict__ ps,
    const int* __restrict__ pidx,
    const float* __restrict__ psm, const int* __restrict__ psi,
    int B, int S, int V, int* __restrict__ out) {
  const int b = blockIdx.x;
  const int lane = threadIdx.x;
  const bool greedy = (topk[b] == 1);

  __shared__ float Ms[4], Zs[4];
  __shared__ int tam[4], rec[4], accs[4];

  if (lane < S) {
    // stats: linear combine over chunks (same order as k_fused -> same M,Z)
    const int row = b * S + lane;
    float M = -INFINITY, Z = 0.f;
    for (int c = 0; c < NCHUNK; ++c)
      comb_ms(M, Z, pm[row * NCHUNK + c], ps[row * NCHUNK + c]);
    Ms[lane] = M; Zs[lane] = Z;
  } else if (lane >= 32 && lane < 32 + S && greedy) {
    const int s = lane - 32;
    const int row = b * S + s;
    float m = -INFINITY; int mi = INT_MAX;
    for (int c = 0; c < NCHUNK; ++c)
      comb_mx(m, mi, pm[row * NCHUNK + c], pidx[row * NCHUNK + c]);
    tam[s] = mi;
  } else if (lane >= 40 && lane < 40 + S && !greedy) {
    const int s = lane - 40;
    const int row = b * S + s;
    float m = -INFINITY; int mi = INT_MAX;
    for (int c = 0; c < NCHUNK; ++c)
      comb_mx(m, mi, psm[row * NCHUNK + c], psi[row * NCHUNK + c]);
    rec[s] = mi;
  }
  __syncthreads();

  if (lane < S && !greedy) {
    const int row = b * S + lane;
    const int tok = dids[row];
    const float t_at = expf(logits[(size_t)row * V + tok] - Ms[lane]) / Zs[lane];
    const float d_at = draft[(size_t)row * V + tok];
    const float u = uniform[row];
    accs[lane] = (d_at > 0.f && (t_at / d_at) >= u) ? 1 : 0;
  }
  __syncthreads();

  if (lane == 0) {
    int tokv[9];
    bool rejected_before = false, any_rej = false;
    for (int ss = 0; ss < S; ++ss) {
      const int r = b * S + ss;
      const int dtok = dids[r];
      int t; bool rej;
      if (greedy) {
        const int ta = tam[ss];
        rej = (dtok != ta);
        t = ta;
      } else {
        const int a = accs[ss];
        rej = !a;
        t = a ? dtok : rec[ss];
      }
      tokv[ss] = rejected_before ? PLACEHOLDER : t;
      any_rej = any_rej || rej;
      rejected_before = rejected_before || rej;
    }
    tokv[S] = any_rej ? PLACEHOLDER : bonus[b];
    int na = 0;
    const int Sp1 = S + 1;
    for (int j = 0; j < Sp1; ++j) na += (tokv[j] != PLACEHOLDER);
    for (int j = 0; j < Sp1; ++j) out[b * Sp1 + j] = tokv[j];
    out[B * Sp1 + b] = Sp1 - na;            // num_rejected_tokens
    out[B * Sp1 + B + b] = tokv[na - 1];    // last_token_ids
  }
}

extern "C" void kernel_launch(void* const* d_in, const int* in_sizes, int n_in,
                              void* d_out, int out_size, void* d_ws, size_t ws_size,
                              hipStream_t stream) {
  const float* logits = (const float*)d_in[0];
  const float* draft  = (const float*)d_in[1];
  const int*   dids   = (const int*)d_in[2];
  const int*   bonus  = (const int*)d_in[3];
  const int*   topk   = (const int*)d_in[4];
  const float* unif   = (const float*)d_in[5];
  const float* invq   = (const float*)d_in[6];
  int* out = (int*)d_out;

  const int B = in_sizes[3];
  const int S = in_sizes[2] / B;
  const int V = in_sizes[0] / in_sizes[2];
  const int nrows = B * S;
  const int nitems = nrows * NCHUNK;
  int chunk_elems = (V + NCHUNK - 1) / NCHUNK;
  chunk_elems = (chunk_elems + 3) & ~3;   // float4-aligned chunk starts

  char* w = (char*)d_ws;
  float* pm   = (float*)w; w += (size_t)nitems * sizeof(float);
  float* ps   = (float*)w; w += (size_t)nitems * sizeof(float);
  int*   pidx = (int*)w;   w += (size_t)nitems * sizeof(int);
  float* psm  = (float*)w; w += (size_t)nitems * sizeof(float);
  int*   psi  = (int*)w;   w += (size_t)nitems * sizeof(int);
  int*   cnt  = (int*)w;   w += (size_t)nrows * sizeof(int);

  // reset row counters each call (graph-replay determinism)
  hipMemsetAsync(cnt, 0, (size_t)nrows * sizeof(int), stream);

  // grid: multiple of NCHUNK so a row's 32 peers share a grid-stride
  // iteration; 2048 = 8 blocks/CU x 256 CUs (16 KB LDS, <=64 VGPR -> all
  // co-resident).
  int grid = nitems < 2048 ? nitems : 2048;
  k_fused<<<dim3(grid), dim3(256), 0, stream>>>(
      logits, draft, topk, invq, pm, ps, pidx, psm, psi, cnt,
      S, V, chunk_elems, nitems);
  k_finalize<<<dim3(B), dim3(64), 0, stream>>>(
      logits, draft, dids, bonus, topk, unif, pm, ps, pidx, psm, psi,
      B, S, V, out);
}

// Round 5
// 64.433 us; speedup vs baseline: 10.5854x; 8.2525x over previous
//
#include <hip/hip_runtime.h>
#include <math.h>
#include <limits.h>

#define NCHUNK 16
#define PLACEHOLDER (-1)

typedef float f32x4 __attribute__((ext_vector_type(4)));

// exp(x - 16), computed as exp2(x*log2e - 16*log2e). No running max needed:
// logits are O(1), so terms are ~1e-7 and the 128K-term sum ~1e-2 -- all
// comfortably inside f32 range. Softmax p = fexp(l) / sum(fexp(l)).
__device__ __forceinline__ float fexp(float x) {
  return exp2f(fmaf(x, 1.44269504088896340736f, -23.0831206542234143f));
}

// (max, index) combine with first-occurrence tie-break (lower index wins).
__device__ __forceinline__ void comb_mx(float& m, int& i, float m2, int i2) {
  if (m2 > m || (m2 == m && i2 < i)) { m = m2; i = i2; }
}

// Pass 1: greedy rows -> per-chunk {max, argmax} (no expf);
//         random rows -> per-chunk sum of exp(l - 16) (branchless).
__global__ __launch_bounds__(256) void k_stats(
    const float* __restrict__ logits, const int* __restrict__ topk,
    float* __restrict__ pm, float* __restrict__ ps, int* __restrict__ pidx,
    int S, int V, int chunk_elems) {
  const int row = blockIdx.y;
  const int chunk = blockIdx.x;
  const int tid = threadIdx.x;
  const int b = row / S;
  const int begin = chunk * chunk_elems;
  const int end = min(begin + chunk_elems, V);
  const int n = max(end - begin, 0);
  const int c4 = n >> 2;
  const float* lrow = logits + (size_t)row * V;
  const f32x4* l4 = (const f32x4*)(lrow + begin);
  const int item = row * NCHUNK + chunk;

  __shared__ float shf[4];
  __shared__ int shi[4];
  const int lane = tid & 63;
  const int wv = tid >> 6;

  if (topk[b] == 1) {
    // ---- greedy: max + argmax only ----
    float m = -INFINITY; int mi = INT_MAX;
    for (int i = tid; i < c4; i += 256) {
      f32x4 v = l4[i];
      const int gi = begin + (i << 2);
#pragma unroll
      for (int k = 0; k < 4; ++k)
        if (v[k] > m) { m = v[k]; mi = gi + k; }   // strict >: first idx kept
    }
    for (int j = begin + (c4 << 2) + tid; j < end; j += 256) {
      float x = lrow[j];
      if (x > m) { m = x; mi = j; }
    }
    for (int off = 32; off; off >>= 1) {
      float m2 = __shfl_xor(m, off);
      int   i2 = __shfl_xor(mi, off);
      comb_mx(m, mi, m2, i2);
    }
    if (lane == 0) { shf[wv] = m; shi[wv] = mi; }
    __syncthreads();
    if (tid == 0) {
#pragma unroll
      for (int w = 1; w < 4; ++w) comb_mx(m, mi, shf[w], shi[w]);
      pm[item] = m; pidx[item] = mi;
    }
  } else {
    // ---- random: branchless sum of exp(l - 16) ----
    float ssum = 0.f;
    for (int i = tid; i < c4; i += 256) {
      f32x4 v = l4[i];
      ssum += fexp(v[0]); ssum += fexp(v[1]);
      ssum += fexp(v[2]); ssum += fexp(v[3]);
    }
    for (int j = begin + (c4 << 2) + tid; j < end; j += 256)
      ssum += fexp(lrow[j]);
    for (int off = 32; off; off >>= 1)
      ssum += __shfl_xor(ssum, off);
    if (lane == 0) shf[wv] = ssum;
    __syncthreads();
    if (tid == 0) {
      float z = shf[0] + shf[1] + shf[2] + shf[3];
      ps[item] = z;
    }
  }
}

// Pass 2 (random rows only): argmax of max(p - d, 0) * invq.
// Z = linear sum of the row's 16 chunk partials (identical order in every
// consumer -> bitwise-identical Z). Logits re-read (should hit L3 from
// pass 1); draft nontemporal (don't evict logits); invq cached (xS reuse).
__global__ __launch_bounds__(256) void k_score(
    const float* __restrict__ logits, const float* __restrict__ draft,
    const float* __restrict__ invq, const int* __restrict__ topk,
    const float* __restrict__ ps,
    int S, int V, int chunk_elems,
    float* __restrict__ psm, int* __restrict__ psi) {
  const int row = blockIdx.y;
  const int chunk = blockIdx.x;
  const int tid = threadIdx.x;
  const int b = row / S;
  const int item = row * NCHUNK + chunk;
  if (topk[b] == 1) return;  // psm/psi unread for greedy rows

  __shared__ float sInvZ;
  __shared__ float shf[4];
  __shared__ int shi[4];
  if (tid == 0) {
    float Z = 0.f;
    for (int c = 0; c < NCHUNK; ++c) Z += ps[row * NCHUNK + c];
    sInvZ = 1.0f / Z;
  }
  __syncthreads();
  const float invZ = sInvZ;

  const int begin = chunk * chunk_elems;
  const int end = min(begin + chunk_elems, V);
  const int n = max(end - begin, 0);
  const int c4 = n >> 2;
  const float* lrow = logits + (size_t)row * V;
  const float* drow = draft + (size_t)row * V;
  const float* qrow = invq + (size_t)b * V;
  const f32x4* l4 = (const f32x4*)(lrow + begin);
  const f32x4* d4 = (const f32x4*)(drow + begin);
  const f32x4* q4 = (const f32x4*)(qrow + begin);

  float smx = -INFINITY; int si = INT_MAX;
  for (int i = tid; i < c4; i += 256) {
    f32x4 lv = l4[i];                               // L3-resident from pass 1
    f32x4 dv = __builtin_nontemporal_load(d4 + i);  // stream
    f32x4 qv = q4[i];                               // reused across S rows
    const int gi = begin + (i << 2);
#pragma unroll
    for (int k = 0; k < 4; ++k) {
      float p = fexp(lv[k]) * invZ;
      float sc = fmaxf(p - dv[k], 0.f) * qv[k];
      if (sc > smx) { smx = sc; si = gi + k; }
    }
  }
  for (int j = begin + (c4 << 2) + tid; j < end; j += 256) {
    float p = fexp(lrow[j]) * invZ;
    float sc = fmaxf(p - drow[j], 0.f) * qrow[j];
    if (sc > smx) { smx = sc; si = j; }
  }

  const int lane = tid & 63;
  const int wv = tid >> 6;
  for (int off = 32; off; off >>= 1) {
    float m2 = __shfl_xor(smx, off);
    int   i2 = __shfl_xor(si, off);
    comb_mx(smx, si, m2, i2);
  }
  if (lane == 0) { shf[wv] = smx; shi[wv] = si; }
  __syncthreads();
  if (tid == 0) {
#pragma unroll
    for (int w = 1; w < 4; ++w) comb_mx(smx, si, shf[w], shi[w]);
    psm[item] = smx; psi[item] = si;
  }
}

// Finalize: one block (64 threads) per batch element b.
__global__ __launch_bounds__(64) void k_finalize(
    const float* __restrict__ logits, const float* __restrict__ draft,
    const int* __restrict__ dids, const int* __restrict__ bonus,
    const int* __restrict__ topk, const float* __restrict__ uniform,
    const float* __restrict__ pm, const float* __restrict__ ps,
    const int* __restrict__ pidx,
    const float* __restrict__ psm, const int* __restrict__ psi,
    int B, int S, int V, int* __restrict__ out) {
  const int b = blockIdx.x;
  const int lane = threadIdx.x;
  const bool greedy = (topk[b] == 1);

  __shared__ int tam[4], rec[4], accs[4];

  if (lane < S) {
    const int row = b * S + lane;
    if (greedy) {
      float m = -INFINITY; int mi = INT_MAX;
      for (int c = 0; c < NCHUNK; ++c)
        comb_mx(m, mi, pm[row * NCHUNK + c], pidx[row * NCHUNK + c]);
      tam[lane] = mi;
    } else {
      // accept decision: t_at = exp(l_tok-16)/Z, identical-order Z sum
      float Z = 0.f;
      for (int c = 0; c < NCHUNK; ++c) Z += ps[row * NCHUNK + c];
      const int tok = dids[row];
      const float t_at = fexp(logits[(size_t)row * V + tok]) / Z;
      const float d_at = draft[(size_t)row * V + tok];
      const float u = uniform[row];
      accs[lane] = (d_at > 0.f && (t_at / d_at) >= u) ? 1 : 0;
      // recovered token: argmax over chunk partials
      float m = -INFINITY; int mi = INT_MAX;
      for (int c = 0; c < NCHUNK; ++c)
        comb_mx(m, mi, psm[row * NCHUNK + c], psi[row * NCHUNK + c]);
      rec[lane] = mi;
    }
  }
  __syncthreads();

  if (lane == 0) {
    int tokv[9];
    bool rejected_before = false, any_rej = false;
    for (int ss = 0; ss < S; ++ss) {
      const int r = b * S + ss;
      const int dtok = dids[r];
      int t; bool rej;
      if (greedy) {
        const int ta = tam[ss];
        rej = (dtok != ta);
        t = ta;
      } else {
        const int a = accs[ss];
        rej = !a;
        t = a ? dtok : rec[ss];
      }
      tokv[ss] = rejected_before ? PLACEHOLDER : t;
      any_rej = any_rej || rej;
      rejected_before = rejected_before || rej;
    }
    tokv[S] = any_rej ? PLACEHOLDER : bonus[b];
    int na = 0;
    const int Sp1 = S + 1;
    for (int j = 0; j < Sp1; ++j) na += (tokv[j] != PLACEHOLDER);
    for (int j = 0; j < Sp1; ++j) out[b * Sp1 + j] = tokv[j];
    out[B * Sp1 + b] = Sp1 - na;            // num_rejected_tokens
    out[B * Sp1 + B + b] = tokv[na - 1];    // last_token_ids
  }
}

extern "C" void kernel_launch(void* const* d_in, const int* in_sizes, int n_in,
                              void* d_out, int out_size, void* d_ws, size_t ws_size,
                              hipStream_t stream) {
  const float* logits = (const float*)d_in[0];
  const float* draft  = (const float*)d_in[1];
  const int*   dids   = (const int*)d_in[2];
  const int*   bonus  = (const int*)d_in[3];
  const int*   topk   = (const int*)d_in[4];
  const float* unif   = (const float*)d_in[5];
  const float* invq   = (const float*)d_in[6];
  int* out = (int*)d_out;

  const int B = in_sizes[3];
  const int S = in_sizes[2] / B;
  const int V = in_sizes[0] / in_sizes[2];
  const int nrows = B * S;
  const int nitems = nrows * NCHUNK;

  char* w = (char*)d_ws;
  float* pm   = (float*)w; w += (size_t)nitems * sizeof(float);
  float* ps   = (float*)w; w += (size_t)nitems * sizeof(float);
  int*   pidx = (int*)w;   w += (size_t)nitems * sizeof(int);
  float* psm  = (float*)w; w += (size_t)nitems * sizeof(float);
  int*   psi  = (int*)w;   w += (size_t)nitems * sizeof(int);

  int chunk_elems = (V + NCHUNK - 1) / NCHUNK;
  chunk_elems = (chunk_elems + 3) & ~3;   // float4-aligned chunk starts

  dim3 grid1(NCHUNK, nrows);
  k_stats<<<grid1, dim3(256), 0, stream>>>(logits, topk, pm, ps, pidx,
                                           S, V, chunk_elems);
  k_score<<<grid1, dim3(256), 0, stream>>>(logits, draft, invq, topk, ps,
                                           S, V, chunk_elems, psm, psi);
  k_finalize<<<dim3(B), dim3(64), 0, stream>>>(
      logits, draft, dids, bonus, topk, unif, pm, ps, pidx, psm, psi,
      B, S, V, out);
}

// Round 6
// 50.787 us; speedup vs baseline: 13.4298x; 1.2687x over previous
//
#include <hip/hip_runtime.h>
#include <math.h>
#include <limits.h>

#define NCHUNK 16
#define PLACEHOLDER (-1)

typedef float f32x4 __attribute__((ext_vector_type(4)));

// exp(x - 16), computed as exp2(x*log2e - 16*log2e). No running max needed:
// logits are O(1), so terms are ~1e-7 and the 128K-term sum ~1e-2 -- all
// comfortably inside f32 range. Softmax p = fexp(l) / sum(fexp(l)).
__device__ __forceinline__ float fexp(float x) {
  return exp2f(fmaf(x, 1.44269504088896340736f, -23.0831206542234143f));
}

// (max, index) combine with first-occurrence tie-break (lower index wins).
__device__ __forceinline__ void comb_mx(float& m, int& i, float m2, int i2) {
  if (m2 > m || (m2 == m && i2 < i)) { m = m2; i = i2; }
}

// Pass 1: greedy rows -> per-chunk {max, argmax} (no expf);
//         random rows -> per-chunk sum of exp(l - 16) (branchless).
__global__ __launch_bounds__(256) void k_stats(
    const float* __restrict__ logits, const int* __restrict__ topk,
    float* __restrict__ pm, float* __restrict__ ps, int* __restrict__ pidx,
    int S, int V, int chunk_elems) {
  const int row = blockIdx.y;
  const int chunk = blockIdx.x;
  const int tid = threadIdx.x;
  const int b = row / S;
  const int begin = chunk * chunk_elems;
  const int end = min(begin + chunk_elems, V);
  const int n = max(end - begin, 0);
  const int c4 = n >> 2;
  const float* lrow = logits + (size_t)row * V;
  const f32x4* l4 = (const f32x4*)(lrow + begin);
  const int item = row * NCHUNK + chunk;

  __shared__ float shf[4];
  __shared__ int shi[4];
  const int lane = tid & 63;
  const int wv = tid >> 6;

  if (topk[b] == 1) {
    // ---- greedy: max + argmax only ----
    float m = -INFINITY; int mi = INT_MAX;
    for (int i = tid; i < c4; i += 256) {
      f32x4 v = l4[i];
      const int gi = begin + (i << 2);
#pragma unroll
      for (int k = 0; k < 4; ++k)
        if (v[k] > m) { m = v[k]; mi = gi + k; }   // strict >: first idx kept
    }
    for (int j = begin + (c4 << 2) + tid; j < end; j += 256) {
      float x = lrow[j];
      if (x > m) { m = x; mi = j; }
    }
    for (int off = 32; off; off >>= 1) {
      float m2 = __shfl_xor(m, off);
      int   i2 = __shfl_xor(mi, off);
      comb_mx(m, mi, m2, i2);
    }
    if (lane == 0) { shf[wv] = m; shi[wv] = mi; }
    __syncthreads();
    if (tid == 0) {
#pragma unroll
      for (int w = 1; w < 4; ++w) comb_mx(m, mi, shf[w], shi[w]);
      pm[item] = m; pidx[item] = mi;
    }
  } else {
    // ---- random: branchless sum of exp(l - 16) ----
    float ssum = 0.f;
    for (int i = tid; i < c4; i += 256) {
      f32x4 v = l4[i];
      ssum += fexp(v[0]); ssum += fexp(v[1]);
      ssum += fexp(v[2]); ssum += fexp(v[3]);
    }
    for (int j = begin + (c4 << 2) + tid; j < end; j += 256)
      ssum += fexp(lrow[j]);
    for (int off = 32; off; off >>= 1)
      ssum += __shfl_xor(ssum, off);
    if (lane == 0) shf[wv] = ssum;
    __syncthreads();
    if (tid == 0)
      ps[item] = shf[0] + shf[1] + shf[2] + shf[3];
  }
}

// Accept decisions + recovery worklist. ONE block. Thread r owns row r:
// Z = linear chunk-sum (same order as k_score -> consistent), t_at via fexp,
// accept test. Then one thread per b marks ONLY the first-rejected row of a
// non-greedy b as needing a recovered token (that is the only recovered
// token the reference ever consumes). Every row's flag is written every
// call (no memset; deterministic under graph replay).
__global__ __launch_bounds__(256) void k_accept(
    const float* __restrict__ logits, const float* __restrict__ draft,
    const int* __restrict__ dids, const int* __restrict__ topk,
    const float* __restrict__ uniform, const float* __restrict__ ps,
    int B, int S, int V, int nrows,
    int* __restrict__ acc, int* __restrict__ needRec) {
  for (int row = threadIdx.x; row < nrows; row += 256) {
    const int b = row / S;
    int a = 1;
    if (topk[b] != 1) {
      float Z = 0.f;
      for (int c = 0; c < NCHUNK; ++c) Z += ps[row * NCHUNK + c];
      const int tok = dids[row];
      const float t_at = fexp(logits[(size_t)row * V + tok]) / Z;
      const float d_at = draft[(size_t)row * V + tok];
      const float u = uniform[row];
      a = (d_at > 0.f && (t_at / d_at) >= u) ? 1 : 0;
    }
    acc[row] = a;
  }
  __syncthreads();
  for (int b = threadIdx.x; b < B; b += 256) {
    const bool greedy = (topk[b] == 1);
    int first = -1;
    for (int ss = 0; ss < S; ++ss)
      if (first < 0 && !acc[b * S + ss]) first = ss;
    for (int ss = 0; ss < S; ++ss)
      needRec[b * S + ss] = (!greedy && ss == first) ? 1 : 0;
  }
}

// Pass 2: recovered-token argmax, ONLY for flagged rows (~1 per non-greedy
// b). Z re-derived with the identical linear chunk-sum. Logits re-read
// (L3-resident from pass 1); draft nontemporal; invq cached.
__global__ __launch_bounds__(256) void k_score(
    const float* __restrict__ logits, const float* __restrict__ draft,
    const float* __restrict__ invq, const int* __restrict__ needRec,
    const float* __restrict__ ps,
    int S, int V, int chunk_elems,
    float* __restrict__ psm, int* __restrict__ psi) {
  const int row = blockIdx.y;
  if (!needRec[row]) return;
  const int chunk = blockIdx.x;
  const int tid = threadIdx.x;
  const int b = row / S;
  const int item = row * NCHUNK + chunk;

  __shared__ float sInvZ;
  __shared__ float shf[4];
  __shared__ int shi[4];
  if (tid == 0) {
    float Z = 0.f;
    for (int c = 0; c < NCHUNK; ++c) Z += ps[row * NCHUNK + c];
    sInvZ = 1.0f / Z;
  }
  __syncthreads();
  const float invZ = sInvZ;

  const int begin = chunk * chunk_elems;
  const int end = min(begin + chunk_elems, V);
  const int n = max(end - begin, 0);
  const int c4 = n >> 2;
  const float* lrow = logits + (size_t)row * V;
  const float* drow = draft + (size_t)row * V;
  const float* qrow = invq + (size_t)b * V;
  const f32x4* l4 = (const f32x4*)(lrow + begin);
  const f32x4* d4 = (const f32x4*)(drow + begin);
  const f32x4* q4 = (const f32x4*)(qrow + begin);

  float smx = -INFINITY; int si = INT_MAX;
  for (int i = tid; i < c4; i += 256) {
    f32x4 lv = l4[i];                               // L3-resident from pass 1
    f32x4 dv = __builtin_nontemporal_load(d4 + i);  // stream
    f32x4 qv = q4[i];
    const int gi = begin + (i << 2);
#pragma unroll
    for (int k = 0; k < 4; ++k) {
      float p = fexp(lv[k]) * invZ;
      float sc = fmaxf(p - dv[k], 0.f) * qv[k];
      if (sc > smx) { smx = sc; si = gi + k; }
    }
  }
  for (int j = begin + (c4 << 2) + tid; j < end; j += 256) {
    float p = fexp(lrow[j]) * invZ;
    float sc = fmaxf(p - drow[j], 0.f) * qrow[j];
    if (sc > smx) { smx = sc; si = j; }
  }

  const int lane = tid & 63;
  const int wv = tid >> 6;
  for (int off = 32; off; off >>= 1) {
    float m2 = __shfl_xor(smx, off);
    int   i2 = __shfl_xor(si, off);
    comb_mx(smx, si, m2, i2);
  }
  if (lane == 0) { shf[wv] = smx; shi[wv] = si; }
  __syncthreads();
  if (tid == 0) {
#pragma unroll
    for (int w = 1; w < 4; ++w) comb_mx(smx, si, shf[w], shi[w]);
    psm[item] = smx; psi[item] = si;
  }
}

// Finalize: one block (64 threads) per batch element b. psm/psi are read
// ONLY for flagged rows (others may hold poison -- never consumed).
__global__ __launch_bounds__(64) void k_finalize(
    const int* __restrict__ dids, const int* __restrict__ bonus,
    const int* __restrict__ topk,
    const float* __restrict__ pm, const int* __restrict__ pidx,
    const float* __restrict__ psm, const int* __restrict__ psi,
    const int* __restrict__ acc, const int* __restrict__ needRec,
    int B, int S, int* __restrict__ out) {
  const int b = blockIdx.x;
  const int lane = threadIdx.x;
  const bool greedy = (topk[b] == 1);

  __shared__ int tam[8], rec[8];

  if (lane < S) {
    const int row = b * S + lane;
    if (greedy) {
      float m = -INFINITY; int mi = INT_MAX;
      for (int c = 0; c < NCHUNK; ++c)
        comb_mx(m, mi, pm[row * NCHUNK + c], pidx[row * NCHUNK + c]);
      tam[lane] = mi;
    } else if (needRec[row]) {
      float m = -INFINITY; int mi = INT_MAX;
      for (int c = 0; c < NCHUNK; ++c)
        comb_mx(m, mi, psm[row * NCHUNK + c], psi[row * NCHUNK + c]);
      rec[lane] = mi;
    } else {
      rec[lane] = 0;   // never consumed
    }
  }
  __syncthreads();

  if (lane == 0) {
    int tokv[9];
    bool rejected_before = false, any_rej = false;
    for (int ss = 0; ss < S; ++ss) {
      const int r = b * S + ss;
      const int dtok = dids[r];
      int t; bool rej;
      if (greedy) {
        const int ta = tam[ss];
        rej = (dtok != ta);
        t = ta;
      } else {
        const int a = acc[r];
        rej = !a;
        t = a ? dtok : rec[ss];
      }
      tokv[ss] = rejected_before ? PLACEHOLDER : t;
      any_rej = any_rej || rej;
      rejected_before = rejected_before || rej;
    }
    tokv[S] = any_rej ? PLACEHOLDER : bonus[b];
    int na = 0;
    const int Sp1 = S + 1;
    for (int j = 0; j < Sp1; ++j) na += (tokv[j] != PLACEHOLDER);
    for (int j = 0; j < Sp1; ++j) out[b * Sp1 + j] = tokv[j];
    out[B * Sp1 + b] = Sp1 - na;            // num_rejected_tokens
    out[B * Sp1 + B + b] = tokv[na - 1];    // last_token_ids
  }
}

extern "C" void kernel_launch(void* const* d_in, const int* in_sizes, int n_in,
                              void* d_out, int out_size, void* d_ws, size_t ws_size,
                              hipStream_t stream) {
  const float* logits = (const float*)d_in[0];
  const float* draft  = (const float*)d_in[1];
  const int*   dids   = (const int*)d_in[2];
  const int*   bonus  = (const int*)d_in[3];
  const int*   topk   = (const int*)d_in[4];
  const float* unif   = (const float*)d_in[5];
  const float* invq   = (const float*)d_in[6];
  int* out = (int*)d_out;

  const int B = in_sizes[3];
  const int S = in_sizes[2] / B;
  const int V = in_sizes[0] / in_sizes[2];
  const int nrows = B * S;
  const int nitems = nrows * NCHUNK;

  char* w = (char*)d_ws;
  float* pm   = (float*)w; w += (size_t)nitems * sizeof(float);
  float* ps   = (float*)w; w += (size_t)nitems * sizeof(float);
  int*   pidx = (int*)w;   w += (size_t)nitems * sizeof(int);
  float* psm  = (float*)w; w += (size_t)nitems * sizeof(float);
  int*   psi  = (int*)w;   w += (size_t)nitems * sizeof(int);
  int*   acc  = (int*)w;   w += (size_t)nrows * sizeof(int);
  int*   nrec = (int*)w;   w += (size_t)nrows * sizeof(int);

  int chunk_elems = (V + NCHUNK - 1) / NCHUNK;
  chunk_elems = (chunk_elems + 3) & ~3;   // float4-aligned chunk starts

  dim3 grid1(NCHUNK, nrows);
  k_stats<<<grid1, dim3(256), 0, stream>>>(logits, topk, pm, ps, pidx,
                                           S, V, chunk_elems);
  k_accept<<<dim3(1), dim3(256), 0, stream>>>(
      logits, draft, dids, topk, unif, ps, B, S, V, nrows, acc, nrec);
  k_score<<<grid1, dim3(256), 0, stream>>>(logits, draft, invq, nrec, ps,
                                           S, V, chunk_elems, psm, psi);
  k_finalize<<<dim3(B), dim3(64), 0, stream>>>(
      dids, bonus, topk, pm, pidx, psm, psi, acc, nrec, B, S, out);
}

// Round 7
// 47.441 us; speedup vs baseline: 14.3768x; 1.0705x over previous
//
#include <hip/hip_runtime.h>
#include <math.h>
#include <limits.h>

#define NCHUNK 16
#define PLACEHOLDER (-1)

typedef float f32x4 __attribute__((ext_vector_type(4)));

// exp(x - 16), computed as exp2(x*log2e - 16*log2e). No running max needed:
// logits are O(1), so terms are ~1e-7 and the 128K-term sum ~1e-2 -- all
// comfortably inside f32 range. Softmax p = fexp(l) / sum(fexp(l)).
__device__ __forceinline__ float fexp(float x) {
  return exp2f(fmaf(x, 1.44269504088896340736f, -23.0831206542234143f));
}

// (max, index) combine with first-occurrence tie-break (lower index wins).
__device__ __forceinline__ void comb_mx(float& m, int& i, float m2, int i2) {
  if (m2 > m || (m2 == m && i2 < i)) { m = m2; i = i2; }
}

// Accept decision for one row. MUST be bitwise-identical wherever called
// (k_score prologue and k_finalize): linear Z sum in chunk order, fexp,
// divide, compare. Returns 1 = accept. Also outputs Z.
__device__ __forceinline__ int accept_row(
    const float* __restrict__ logits, const float* __restrict__ draft,
    const int* __restrict__ dids, const float* __restrict__ uniform,
    const float* __restrict__ ps, int row, int V, float& Zout) {
  float Z = 0.f;
#pragma unroll
  for (int c = 0; c < NCHUNK; ++c) Z += ps[row * NCHUNK + c];
  Zout = Z;
  const int tok = dids[row];
  const float t_at = fexp(logits[(size_t)row * V + tok]) / Z;
  const float d_at = draft[(size_t)row * V + tok];
  const float u = uniform[row];
  return (d_at > 0.f && (t_at / d_at) >= u) ? 1 : 0;
}

// Pass 1: greedy rows -> per-chunk {max, argmax} (no expf);
//         random rows -> per-chunk sum of exp(l - 16) (branchless).
__global__ __launch_bounds__(256) void k_stats(
    const float* __restrict__ logits, const int* __restrict__ topk,
    float* __restrict__ pm, float* __restrict__ ps, int* __restrict__ pidx,
    int S, int V, int chunk_elems) {
  const int row = blockIdx.y;
  const int chunk = blockIdx.x;
  const int tid = threadIdx.x;
  const int b = row / S;
  const int begin = chunk * chunk_elems;
  const int end = min(begin + chunk_elems, V);
  const int n = max(end - begin, 0);
  const int c4 = n >> 2;
  const float* lrow = logits + (size_t)row * V;
  const f32x4* l4 = (const f32x4*)(lrow + begin);
  const int item = row * NCHUNK + chunk;

  __shared__ float shf[4];
  __shared__ int shi[4];
  const int lane = tid & 63;
  const int wv = tid >> 6;

  if (topk[b] == 1) {
    // ---- greedy: max + argmax only ----
    float m = -INFINITY; int mi = INT_MAX;
    for (int i = tid; i < c4; i += 256) {
      f32x4 v = l4[i];
      const int gi = begin + (i << 2);
#pragma unroll
      for (int k = 0; k < 4; ++k)
        if (v[k] > m) { m = v[k]; mi = gi + k; }   // strict >: first idx kept
    }
    for (int j = begin + (c4 << 2) + tid; j < end; j += 256) {
      float x = lrow[j];
      if (x > m) { m = x; mi = j; }
    }
    for (int off = 32; off; off >>= 1) {
      float m2 = __shfl_xor(m, off);
      int   i2 = __shfl_xor(mi, off);
      comb_mx(m, mi, m2, i2);
    }
    if (lane == 0) { shf[wv] = m; shi[wv] = mi; }
    __syncthreads();
    if (tid == 0) {
#pragma unroll
      for (int w = 1; w < 4; ++w) comb_mx(m, mi, shf[w], shi[w]);
      pm[item] = m; pidx[item] = mi;
    }
  } else {
    // ---- random: branchless sum of exp(l - 16) ----
    float ssum = 0.f;
    for (int i = tid; i < c4; i += 256) {
      f32x4 v = l4[i];
      ssum += fexp(v[0]); ssum += fexp(v[1]);
      ssum += fexp(v[2]); ssum += fexp(v[3]);
    }
    for (int j = begin + (c4 << 2) + tid; j < end; j += 256)
      ssum += fexp(lrow[j]);
    for (int off = 32; off; off >>= 1)
      ssum += __shfl_xor(ssum, off);
    if (lane == 0) shf[wv] = ssum;
    __syncthreads();
    if (tid == 0)
      ps[item] = shf[0] + shf[1] + shf[2] + shf[3];
  }
}

// Pass 2: recovered-token argmax, ONLY for the first-rejected row of each
// non-greedy b (the only recovered token the reference consumes). Each
// block derives the worklist itself in a short prologue (redundant but
// L2-resident); no separate accept kernel, no sync counters.
__global__ __launch_bounds__(256) void k_score(
    const float* __restrict__ logits, const float* __restrict__ draft,
    const float* __restrict__ invq, const int* __restrict__ topk,
    const int* __restrict__ dids, const float* __restrict__ uniform,
    const float* __restrict__ ps,
    int S, int V, int chunk_elems,
    float* __restrict__ psm, int* __restrict__ psi) {
  const int row = blockIdx.y;
  const int b = row / S;
  if (topk[b] == 1) return;
  const int tid = threadIdx.x;
  const int chunk = blockIdx.x;
  const int item = row * NCHUNK + chunk;
  const int ownS = row - b * S;

  // ---- prologue: am I the first-rejected row of b? ----
  __shared__ float sInvZ;
  __shared__ int sGo;
  if (tid < 64) {
    int a = 1; float Z = 1.f;
    if (tid < S)
      a = accept_row(logits, draft, dids, uniform, ps, b * S + tid, V, Z);
    unsigned long long rej = __ballot(a == 0);
    int first = rej ? (int)__ffsll(rej) - 1 : -1;
    if (tid == 0) sGo = (first == ownS);
    if (tid == ownS) sInvZ = 1.0f / Z;
  }
  __syncthreads();
  if (!sGo) return;
  const float invZ = sInvZ;

  const int begin = chunk * chunk_elems;
  const int end = min(begin + chunk_elems, V);
  const int n = max(end - begin, 0);
  const int c4 = n >> 2;
  const float* lrow = logits + (size_t)row * V;
  const float* drow = draft + (size_t)row * V;
  const float* qrow = invq + (size_t)b * V;
  const f32x4* l4 = (const f32x4*)(lrow + begin);
  const f32x4* d4 = (const f32x4*)(drow + begin);
  const f32x4* q4 = (const f32x4*)(qrow + begin);

  __shared__ float shf[4];
  __shared__ int shi[4];
  float smx = -INFINITY; int si = INT_MAX;
  for (int i = tid; i < c4; i += 256) {
    f32x4 lv = l4[i];                               // L3-resident from pass 1
    f32x4 dv = __builtin_nontemporal_load(d4 + i);  // stream
    f32x4 qv = q4[i];
    const int gi = begin + (i << 2);
#pragma unroll
    for (int k = 0; k < 4; ++k) {
      float p = fexp(lv[k]) * invZ;
      float sc = fmaxf(p - dv[k], 0.f) * qv[k];
      if (sc > smx) { smx = sc; si = gi + k; }
    }
  }
  for (int j = begin + (c4 << 2) + tid; j < end; j += 256) {
    float p = fexp(lrow[j]) * invZ;
    float sc = fmaxf(p - drow[j], 0.f) * qrow[j];
    if (sc > smx) { smx = sc; si = j; }
  }

  const int lane = tid & 63;
  const int wv = tid >> 6;
  for (int off = 32; off; off >>= 1) {
    float m2 = __shfl_xor(smx, off);
    int   i2 = __shfl_xor(si, off);
    comb_mx(smx, si, m2, i2);
  }
  if (lane == 0) { shf[wv] = smx; shi[wv] = si; }
  __syncthreads();
  if (tid == 0) {
#pragma unroll
    for (int w = 1; w < 4; ++w) comb_mx(smx, si, shf[w], shi[w]);
    psm[item] = smx; psi[item] = si;
  }
}

// Finalize: one block (64 threads) per batch element b. Recomputes accept
// bits with code identical to k_score's prologue; reads psm/psi ONLY for
// the first-rejected row (the one k_score populated).
__global__ __launch_bounds__(64) void k_finalize(
    const float* __restrict__ logits, const float* __restrict__ draft,
    const int* __restrict__ dids, const int* __restrict__ bonus,
    const int* __restrict__ topk, const float* __restrict__ uniform,
    const float* __restrict__ pm, const int* __restrict__ pidx,
    const float* __restrict__ ps,
    const float* __restrict__ psm, const int* __restrict__ psi,
    int B, int S, int V, int* __restrict__ out) {
  const int b = blockIdx.x;
  const int lane = threadIdx.x;
  const bool greedy = (topk[b] == 1);

  __shared__ int tam[8];
  __shared__ int sFirst, sAccMask;

  if (greedy) {
    if (lane < S) {
      const int row = b * S + lane;
      float m = -INFINITY; int mi = INT_MAX;
#pragma unroll
      for (int c = 0; c < NCHUNK; ++c)
        comb_mx(m, mi, pm[row * NCHUNK + c], pidx[row * NCHUNK + c]);
      tam[lane] = mi;
    }
  } else {
    int a = 1; float Z;
    if (lane < S)
      a = accept_row(logits, draft, dids, uniform, ps, b * S + lane, V, Z);
    unsigned long long rej = __ballot(a == 0);
    unsigned long long accm = __ballot(a != 0);
    if (lane == 0) {
      sFirst = rej ? (int)__ffsll(rej) - 1 : -1;
      sAccMask = (int)(accm & ((1u << S) - 1));
    }
  }
  __syncthreads();

  if (lane == 0) {
    int tokv[9];
    bool rejected_before = false, any_rej = false;
    int first = greedy ? -1 : sFirst;
    int rectok = 0;
    if (!greedy && first >= 0) {
      const int row = b * S + first;
      float m = -INFINITY; int mi = INT_MAX;
#pragma unroll
      for (int c = 0; c < NCHUNK; ++c)
        comb_mx(m, mi, psm[row * NCHUNK + c], psi[row * NCHUNK + c]);
      rectok = mi;
    }
    for (int ss = 0; ss < S; ++ss) {
      const int r = b * S + ss;
      const int dtok = dids[r];
      int t; bool rej;
      if (greedy) {
        const int ta = tam[ss];
        rej = (dtok != ta);
        t = ta;
      } else {
        rej = (ss == first);
        t = rej ? rectok : dtok;
        // positions after first are placeholders anyway
      }
      tokv[ss] = rejected_before ? PLACEHOLDER : t;
      any_rej = any_rej || rej;
      rejected_before = rejected_before || rej;
    }
    tokv[S] = any_rej ? PLACEHOLDER : bonus[b];
    int na = 0;
    const int Sp1 = S + 1;
    for (int j = 0; j < Sp1; ++j) na += (tokv[j] != PLACEHOLDER);
    for (int j = 0; j < Sp1; ++j) out[b * Sp1 + j] = tokv[j];
    out[B * Sp1 + b] = Sp1 - na;            // num_rejected_tokens
    out[B * Sp1 + B + b] = tokv[na - 1];    // last_token_ids
  }
}

extern "C" void kernel_launch(void* const* d_in, const int* in_sizes, int n_in,
                              void* d_out, int out_size, void* d_ws, size_t ws_size,
                              hipStream_t stream) {
  const float* logits = (const float*)d_in[0];
  const float* draft  = (const float*)d_in[1];
  const int*   dids   = (const int*)d_in[2];
  const int*   bonus  = (const int*)d_in[3];
  const int*   topk   = (const int*)d_in[4];
  const float* unif   = (const float*)d_in[5];
  const float* invq   = (const float*)d_in[6];
  int* out = (int*)d_out;

  const int B = in_sizes[3];
  const int S = in_sizes[2] / B;
  const int V = in_sizes[0] / in_sizes[2];
  const int nrows = B * S;
  const int nitems = nrows * NCHUNK;

  char* w = (char*)d_ws;
  float* pm   = (float*)w; w += (size_t)nitems * sizeof(float);
  float* ps   = (float*)w; w += (size_t)nitems * sizeof(float);
  int*   pidx = (int*)w;   w += (size_t)nitems * sizeof(int);
  float* psm  = (float*)w; w += (size_t)nitems * sizeof(float);
  int*   psi  = (int*)w;   w += (size_t)nitems * sizeof(int);

  int chunk_elems = (V + NCHUNK - 1) / NCHUNK;
  chunk_elems = (chunk_elems + 3) & ~3;   // float4-aligned chunk starts

  dim3 grid1(NCHUNK, nrows);
  k_stats<<<grid1, dim3(256), 0, stream>>>(logits, topk, pm, ps, pidx,
                                           S, V, chunk_elems);
  k_score<<<grid1, dim3(256), 0, stream>>>(
      logits, draft, invq, topk, dids, unif, ps, S, V, chunk_elems, psm, psi);
  k_finalize<<<dim3(B), dim3(64), 0, stream>>>(
      logits, draft, dids, bonus, topk, unif, pm, pidx, ps, psm, psi,
      B, S, V, out);
}